// Round 9
// baseline (25.105 us; speedup 1.0000x reference)
//
#include <hip/hip_runtime.h>
#include <math.h>

#define RES 2048
#define NB  256

typedef _Float16 f16;
typedef _Float16 f16x8 __attribute__((ext_vector_type(8)));
typedef float    f32x16 __attribute__((ext_vector_type(16)));

#define BM 128
#define BN 128
#define BK 16
#define NKT (NB / BK)      // 16 k-tiles
#define PL  (BM * BK)      // elements per plane (2048)

__device__ __forceinline__ f16x8 neg8(f16x8 v) {
    union { f16x8 h; unsigned int u[4]; } x;
    x.h = v;
    #pragma unroll
    for (int i = 0; i < 4; ++i) x.u[i] ^= 0x80008000u;
    return x.h;
}

// XOR-swizzled element offset within a [128][16] f16 plane.
// e = idx ^ ((row&7)<<3): element bits 3-5 ^= row bits 0-2 (which are idx
// bits 4-6) -> upper-triangular bit map, bijective. Fragment ds_read_b128
// bank starts for lanes 0..7 become {0,12,24,20,16,28,8,4} (all distinct);
// EVAL u32 writes stay <=2-way (free). Groups of 8 elements at k=0/8 remain
// contiguous and 16B-aligned (bits 0-2 untouched).
__device__ __forceinline__ int swzE(int row, int k) {
    return (row * BK + k) ^ ((row & 7) << 3);
}

// ---------------------------------------------------------------------------
// Fully fused kernel: no global staging, no workspace, one launch.
// E[i,j] = sum_b A(i,b)*B(j,b)  (complex),  out = |E|^2, with
//   A(i,b) = (re+i*im)*exp(-(x_i-x0)^2/s^2)*exp(i*kx*x_i)
//   B(j,b) =            exp(-(y_j-y0)^2/s^2)*exp(i*ky*y_j)
// Each block (128x128 tile) evaluates its A/B panels per 16-beam k-tile
// directly into swizzled LDS (fp16), then consumes with mfma_32x32x16_f16.
// 512 threads = 8 waves (2M x 4N), wave tile 64x32, one barrier per k-tile.
// ---------------------------------------------------------------------------
__global__ __launch_bounds__(512) void ewald_fused(
    const float* __restrict__ theta, const float* __restrict__ reA,
    const float* __restrict__ imA, const float* __restrict__ x0A,
    const float* __restrict__ y0A, const float* __restrict__ lsA,
    const float* __restrict__ X, const float* __restrict__ Y,
    float* __restrict__ out)
{
    __shared__ f16 smA[2][2][PL];   // [buf][Re/Im][swizzled row*16+k]
    __shared__ f16 smB[2][2][PL];
    __shared__ float4 sP0[NB];      // {kx, ky, px, py}
    __shared__ float4 sP1[NB];      // {re, im, 1/sigma^2, -}
    __shared__ float sX[BM], sY[BN];

    const int t    = threadIdx.x;
    const int lane = t & 63;
    const int wave = t >> 6;       // 0..7
    const int wm   = wave >> 2;    // 0..1 -> M offset 64
    const int wn   = wave & 3;     // 0..3 -> N offset 32
    const int la   = lane & 31;
    const int lg   = lane >> 5;

    // XCD-aware swizzle (256 blocks, 8 XCDs)
    const int flat = blockIdx.x;
    const int swz  = (flat & 7) * 32 + (flat >> 3);
    const int m0   = (swz >> 4) * BM;
    const int n0   = (swz & 15) * BN;

    // ---- prologue: per-beam packed params + axis coordinates into LDS ----
    if (t < 128) {
        sX[t] = X[(size_t)(m0 + t) * RES];   // X[i][0] = x_i (indexing='ij')
    } else if (t < 256) {
        sY[t - 128] = Y[n0 + (t - 128)];     // Y[0][j] = y_j
    } else {
        const int b = t - 256;
        float s, c;
        __sincosf(theta[b], &s, &c);
        const float sig = __expf(lsA[b]) + 0.001f;
        sP0[b] = make_float4(50.0f * c, 50.0f * s, x0A[b], y0A[b]);
        sP1[b] = make_float4(reA[b], imA[b], 1.0f / (sig * sig), 0.0f);
    }
    __syncthreads();

    // ---- eval mapping: thread -> 2 beams (kk2, kk2+1) x 2 rows ----
    const int kk2 = (t & 7) * 2;   // beam pair within k-tile
    const int grp = t >> 3;        // 0..63 -> rows grp*2, grp*2+1

    #define EVAL(bf, kt)                                                      \
    do {                                                                      \
        const int b0_ = (kt) * BK + kk2;                                      \
        float aR_[2][2], aI_[2][2], bR_[2][2], bI_[2][2];                     \
        _Pragma("unroll")                                                     \
        for (int jb = 0; jb < 2; ++jb) {                                      \
            const float4 p0 = sP0[b0_ + jb];                                  \
            const float4 p1 = sP1[b0_ + jb];                                  \
            _Pragma("unroll")                                                 \
            for (int r = 0; r < 2; ++r) {                                     \
                const int row = grp * 2 + r;                                  \
                float s_, c_;                                                 \
                const float xv = sX[row];                                     \
                __sincosf(p0.x * xv, &s_, &c_);                               \
                const float dx = xv - p0.z;                                   \
                const float ex = __expf(-dx * dx * p1.z);                     \
                aR_[jb][r] = ex * (p1.x * c_ - p1.y * s_);                    \
                aI_[jb][r] = ex * (p1.x * s_ + p1.y * c_);                    \
                const float yv = sY[row];                                     \
                __sincosf(p0.y * yv, &s_, &c_);                               \
                const float dy = yv - p0.w;                                   \
                const float ey = __expf(-dy * dy * p1.z);                     \
                bR_[jb][r] = ey * c_;                                         \
                bI_[jb][r] = ey * s_;                                         \
            }                                                                 \
        }                                                                     \
        _Pragma("unroll")                                                     \
        for (int r = 0; r < 2; ++r) {                                         \
            const int row = grp * 2 + r;                                      \
            const int e_ = swzE(row, kk2);                                    \
            union { f16 h[2]; unsigned int u; } p_;                           \
            p_.h[0] = (f16)aR_[0][r]; p_.h[1] = (f16)aR_[1][r];               \
            *(unsigned int*)&smA[bf][0][e_] = p_.u;                           \
            p_.h[0] = (f16)aI_[0][r]; p_.h[1] = (f16)aI_[1][r];               \
            *(unsigned int*)&smA[bf][1][e_] = p_.u;                           \
            p_.h[0] = (f16)bR_[0][r]; p_.h[1] = (f16)bR_[1][r];               \
            *(unsigned int*)&smB[bf][0][e_] = p_.u;                           \
            p_.h[0] = (f16)bI_[0][r]; p_.h[1] = (f16)bI_[1][r];               \
            *(unsigned int*)&smB[bf][1][e_] = p_.u;                           \
        }                                                                     \
    } while (0)

    // ---- fragment LDS element-offsets (swizzled, within a plane) ----
    const int offA0 = swzE(wm * 64 +  0 + la, lg * 8);
    const int offA1 = swzE(wm * 64 + 32 + la, lg * 8);
    const int offB  = swzE(wn * 32 + la, lg * 8);

    f32x16 accRe0 = (f32x16)0.0f, accIm0 = (f32x16)0.0f;
    f32x16 accRe1 = (f32x16)0.0f, accIm1 = (f32x16)0.0f;

    // ---- k-tile 0 ----
    EVAL(0, 0);
    __syncthreads();

    for (int kt = 0; kt < NKT; ++kt) {
        const int cur = kt & 1;
        const f16x8 aR0 = *(const f16x8*)&smA[cur][0][offA0];
        const f16x8 aR1 = *(const f16x8*)&smA[cur][0][offA1];
        const f16x8 aI0 = *(const f16x8*)&smA[cur][1][offA0];
        const f16x8 aI1 = *(const f16x8*)&smA[cur][1][offA1];
        const f16x8 bR  = *(const f16x8*)&smB[cur][0][offB];
        const f16x8 bI  = *(const f16x8*)&smB[cur][1][offB];
        const f16x8 bN  = neg8(bI);

        // evaluate next k-tile on the VALU into the OTHER buffer (safe: all
        // waves finished reading it at the previous barrier)
        if (kt + 1 < NKT)
            EVAL(cur ^ 1, kt + 1);

        __builtin_amdgcn_s_setprio(1);
        accRe0 = __builtin_amdgcn_mfma_f32_32x32x16_f16(aR0, bR, accRe0, 0, 0, 0);
        accIm0 = __builtin_amdgcn_mfma_f32_32x32x16_f16(aR0, bI, accIm0, 0, 0, 0);
        accRe1 = __builtin_amdgcn_mfma_f32_32x32x16_f16(aR1, bR, accRe1, 0, 0, 0);
        accIm1 = __builtin_amdgcn_mfma_f32_32x32x16_f16(aR1, bI, accIm1, 0, 0, 0);
        accRe0 = __builtin_amdgcn_mfma_f32_32x32x16_f16(aI0, bN, accRe0, 0, 0, 0);
        accIm0 = __builtin_amdgcn_mfma_f32_32x32x16_f16(aI0, bR, accIm0, 0, 0, 0);
        accRe1 = __builtin_amdgcn_mfma_f32_32x32x16_f16(aI1, bN, accRe1, 0, 0, 0);
        accIm1 = __builtin_amdgcn_mfma_f32_32x32x16_f16(aI1, bR, accIm1, 0, 0, 0);
        __builtin_amdgcn_s_setprio(0);

        __syncthreads();
    }

    // ---- epilogue: out = Re^2 + Im^2 ----
    // C/D layout (32x32): col = lane&31, row = (reg&3) + 8*(reg>>2) + 4*(lane>>5)
    const int gn     = n0 + wn * 32 + la;
    const int gmBase = m0 + wm * 64;
    #pragma unroll
    for (int r = 0; r < 16; ++r) {
        const int row = (r & 3) + 8 * (r >> 2) + 4 * lg;
        const float er = accRe0[r], ei = accIm0[r];
        out[(size_t)(gmBase + row) * RES + gn] = er * er + ei * ei;
    }
    #pragma unroll
    for (int r = 0; r < 16; ++r) {
        const int row = (r & 3) + 8 * (r >> 2) + 4 * lg;
        const float er = accRe1[r], ei = accIm1[r];
        out[(size_t)(gmBase + 32 + row) * RES + gn] = er * er + ei * ei;
    }
    #undef EVAL
}

// ---------------------------------------------------------------------------
extern "C" void kernel_launch(void* const* d_in, const int* in_sizes, int n_in,
                              void* d_out, int out_size, void* d_ws, size_t ws_size,
                              hipStream_t stream) {
    const float* theta = (const float*)d_in[0];
    const float* reA   = (const float*)d_in[1];
    const float* imA   = (const float*)d_in[2];
    const float* x0A   = (const float*)d_in[3];
    const float* y0A   = (const float*)d_in[4];
    const float* lsA   = (const float*)d_in[5];
    const float* X     = (const float*)d_in[6];
    const float* Y     = (const float*)d_in[7];
    float* out = (float*)d_out;

    ewald_fused<<<256, 512, 0, stream>>>(theta, reA, imA, x0A, y0A, lsA,
                                         X, Y, out);
}

// Round 10
// 23.189 us; speedup vs baseline: 1.0826x; 1.0826x over previous
//
#include <hip/hip_runtime.h>
#include <math.h>

#define RES 2048
#define NB  256

typedef _Float16 f16;
typedef _Float16 f16x8 __attribute__((ext_vector_type(8)));
typedef float    f32x16 __attribute__((ext_vector_type(16)));

#define BM 128
#define BN 128
#define BK 16
#define NKT (NB / BK)      // 16 k-tiles
#define PL  (BM * BK)      // elements per plane (2048)

__device__ __forceinline__ f16x8 neg8(f16x8 v) {
    union { f16x8 h; unsigned int u[4]; } x;
    x.h = v;
    #pragma unroll
    for (int i = 0; i < 4; ++i) x.u[i] ^= 0x80008000u;
    return x.h;
}

// XOR-swizzled element offset within a [128][16] f16 plane (bijective;
// fragment ds_read_b128 conflict-free, EVAL u32 writes <=2-way).
__device__ __forceinline__ int swzE(int row, int k) {
    return (row * BK + k) ^ ((row & 7) << 3);
}

// ---------------------------------------------------------------------------
// Fully fused kernel. E[i,j] = sum_b A(i,b)*B(j,b) (complex), out = |E|^2.
//   A(i,b) = (re+i*im)*exp(-(x_i-x0)^2/s^2)*exp(i*kx*x_i)
//   B(j,b) =            exp(-(y_j-y0)^2/s^2)*exp(i*ky*y_j)
// Per 16-beam k-tile each block evaluates its A/B panels into swizzled LDS
// (fp16) with NATIVE v_sin/v_cos/v_exp (__sinf/__cosf/__expf — NOT
// __sincosf, which resolves to the precise ocml sincos and was ~3x the
// eval cost), then consumes with mfma_32x32x16_f16.
// 512 threads = 8 waves (2M x 4N), wave tile 64x32, one barrier per k-tile.
// ---------------------------------------------------------------------------
__global__ __launch_bounds__(512) void ewald_fused(
    const float* __restrict__ theta, const float* __restrict__ reA,
    const float* __restrict__ imA, const float* __restrict__ x0A,
    const float* __restrict__ y0A, const float* __restrict__ lsA,
    const float* __restrict__ X, const float* __restrict__ Y,
    float* __restrict__ out)
{
    __shared__ f16 smA[2][2][PL];   // [buf][Re/Im][swizzled row*16+k]
    __shared__ f16 smB[2][2][PL];
    __shared__ float4 sP0[NB];      // {kx, ky, px, py}
    __shared__ float4 sP1[NB];      // {re, im, 1/sigma^2, -}
    __shared__ float sX[BM], sY[BN];

    const int t    = threadIdx.x;
    const int lane = t & 63;
    const int wave = t >> 6;       // 0..7
    const int wm   = wave >> 2;    // 0..1 -> M offset 64
    const int wn   = wave & 3;     // 0..3 -> N offset 32
    const int la   = lane & 31;
    const int lg   = lane >> 5;

    // XCD-aware swizzle (256 blocks, 8 XCDs)
    const int flat = blockIdx.x;
    const int swz  = (flat & 7) * 32 + (flat >> 3);
    const int m0   = (swz >> 4) * BM;
    const int n0   = (swz & 15) * BN;

    // ---- prologue: per-beam packed params + axis coordinates into LDS ----
    if (t < 128) {
        sX[t] = X[(size_t)(m0 + t) * RES];   // X[i][0] = x_i (indexing='ij')
    } else if (t < 256) {
        sY[t - 128] = Y[n0 + (t - 128)];     // Y[0][j] = y_j
    } else {
        const int b = t - 256;
        const float th = theta[b];
        const float s = __sinf(th), c = __cosf(th);
        const float sig = __expf(lsA[b]) + 0.001f;
        sP0[b] = make_float4(50.0f * c, 50.0f * s, x0A[b], y0A[b]);
        sP1[b] = make_float4(reA[b], imA[b], 1.0f / (sig * sig), 0.0f);
    }
    __syncthreads();

    // ---- eval mapping: thread -> 2 beams (kk2, kk2+1) x 2 rows ----
    const int kk2 = (t & 7) * 2;   // beam pair within k-tile
    const int grp = t >> 3;        // 0..63 -> rows grp*2, grp*2+1

    #define EVAL(bf, kt)                                                      \
    do {                                                                      \
        const int b0_ = (kt) * BK + kk2;                                      \
        float aR_[2][2], aI_[2][2], bR_[2][2], bI_[2][2];                     \
        _Pragma("unroll")                                                     \
        for (int jb = 0; jb < 2; ++jb) {                                      \
            const float4 p0 = sP0[b0_ + jb];                                  \
            const float4 p1 = sP1[b0_ + jb];                                  \
            _Pragma("unroll")                                                 \
            for (int r = 0; r < 2; ++r) {                                     \
                const int row = grp * 2 + r;                                  \
                const float xv = sX[row];                                     \
                const float phx = p0.x * xv;                                  \
                const float sx_ = __sinf(phx), cx_ = __cosf(phx);             \
                const float dx = xv - p0.z;                                   \
                const float ex = __expf(-dx * dx * p1.z);                     \
                aR_[jb][r] = ex * (p1.x * cx_ - p1.y * sx_);                  \
                aI_[jb][r] = ex * (p1.x * sx_ + p1.y * cx_);                  \
                const float yv = sY[row];                                     \
                const float phy = p0.y * yv;                                  \
                const float sy_ = __sinf(phy), cy_ = __cosf(phy);             \
                const float dy = yv - p0.w;                                   \
                const float ey = __expf(-dy * dy * p1.z);                     \
                bR_[jb][r] = ey * cy_;                                        \
                bI_[jb][r] = ey * sy_;                                        \
            }                                                                 \
        }                                                                     \
        _Pragma("unroll")                                                     \
        for (int r = 0; r < 2; ++r) {                                         \
            const int row = grp * 2 + r;                                      \
            const int e_ = swzE(row, kk2);                                    \
            union { f16 h[2]; unsigned int u; } p_;                           \
            p_.h[0] = (f16)aR_[0][r]; p_.h[1] = (f16)aR_[1][r];               \
            *(unsigned int*)&smA[bf][0][e_] = p_.u;                           \
            p_.h[0] = (f16)aI_[0][r]; p_.h[1] = (f16)aI_[1][r];               \
            *(unsigned int*)&smA[bf][1][e_] = p_.u;                           \
            p_.h[0] = (f16)bR_[0][r]; p_.h[1] = (f16)bR_[1][r];               \
            *(unsigned int*)&smB[bf][0][e_] = p_.u;                           \
            p_.h[0] = (f16)bI_[0][r]; p_.h[1] = (f16)bI_[1][r];               \
            *(unsigned int*)&smB[bf][1][e_] = p_.u;                           \
        }                                                                     \
    } while (0)

    // ---- fragment LDS element-offsets (swizzled, within a plane) ----
    const int offA0 = swzE(wm * 64 +  0 + la, lg * 8);
    const int offA1 = swzE(wm * 64 + 32 + la, lg * 8);
    const int offB  = swzE(wn * 32 + la, lg * 8);

    f32x16 accRe0 = (f32x16)0.0f, accIm0 = (f32x16)0.0f;
    f32x16 accRe1 = (f32x16)0.0f, accIm1 = (f32x16)0.0f;

    // ---- k-tile 0 ----
    EVAL(0, 0);
    __syncthreads();

    for (int kt = 0; kt < NKT; ++kt) {
        const int cur = kt & 1;
        const f16x8 aR0 = *(const f16x8*)&smA[cur][0][offA0];
        const f16x8 aR1 = *(const f16x8*)&smA[cur][0][offA1];
        const f16x8 aI0 = *(const f16x8*)&smA[cur][1][offA0];
        const f16x8 aI1 = *(const f16x8*)&smA[cur][1][offA1];
        const f16x8 bR  = *(const f16x8*)&smB[cur][0][offB];
        const f16x8 bI  = *(const f16x8*)&smB[cur][1][offB];
        const f16x8 bN  = neg8(bI);

        // evaluate next k-tile on the VALU into the OTHER buffer (safe: all
        // waves finished reading it at the previous barrier)
        if (kt + 1 < NKT)
            EVAL(cur ^ 1, kt + 1);

        __builtin_amdgcn_s_setprio(1);
        accRe0 = __builtin_amdgcn_mfma_f32_32x32x16_f16(aR0, bR, accRe0, 0, 0, 0);
        accIm0 = __builtin_amdgcn_mfma_f32_32x32x16_f16(aR0, bI, accIm0, 0, 0, 0);
        accRe1 = __builtin_amdgcn_mfma_f32_32x32x16_f16(aR1, bR, accRe1, 0, 0, 0);
        accIm1 = __builtin_amdgcn_mfma_f32_32x32x16_f16(aR1, bI, accIm1, 0, 0, 0);
        accRe0 = __builtin_amdgcn_mfma_f32_32x32x16_f16(aI0, bN, accRe0, 0, 0, 0);
        accIm0 = __builtin_amdgcn_mfma_f32_32x32x16_f16(aI0, bR, accIm0, 0, 0, 0);
        accRe1 = __builtin_amdgcn_mfma_f32_32x32x16_f16(aI1, bN, accRe1, 0, 0, 0);
        accIm1 = __builtin_amdgcn_mfma_f32_32x32x16_f16(aI1, bR, accIm1, 0, 0, 0);
        __builtin_amdgcn_s_setprio(0);

        __syncthreads();
    }

    // ---- epilogue: out = Re^2 + Im^2 ----
    // C/D layout (32x32): col = lane&31, row = (reg&3) + 8*(reg>>2) + 4*(lane>>5)
    const int gn     = n0 + wn * 32 + la;
    const int gmBase = m0 + wm * 64;
    #pragma unroll
    for (int r = 0; r < 16; ++r) {
        const int row = (r & 3) + 8 * (r >> 2) + 4 * lg;
        const float er = accRe0[r], ei = accIm0[r];
        out[(size_t)(gmBase + row) * RES + gn] = er * er + ei * ei;
    }
    #pragma unroll
    for (int r = 0; r < 16; ++r) {
        const int row = (r & 3) + 8 * (r >> 2) + 4 * lg;
        const float er = accRe1[r], ei = accIm1[r];
        out[(size_t)(gmBase + 32 + row) * RES + gn] = er * er + ei * ei;
    }
    #undef EVAL
}

// ---------------------------------------------------------------------------
extern "C" void kernel_launch(void* const* d_in, const int* in_sizes, int n_in,
                              void* d_out, int out_size, void* d_ws, size_t ws_size,
                              hipStream_t stream) {
    const float* theta = (const float*)d_in[0];
    const float* reA   = (const float*)d_in[1];
    const float* imA   = (const float*)d_in[2];
    const float* x0A   = (const float*)d_in[3];
    const float* y0A   = (const float*)d_in[4];
    const float* lsA   = (const float*)d_in[5];
    const float* X     = (const float*)d_in[6];
    const float* Y     = (const float*)d_in[7];
    float* out = (float*)d_out;

    ewald_fused<<<256, 512, 0, stream>>>(theta, reA, imA, x0A, y0A, lsA,
                                         X, Y, out);
}